// Round 1
// baseline (1707.649 us; speedup 1.0000x reference)
//
#include <hip/hip_runtime.h>
#include <math.h>

#define N_UE 16384
#define N_AP 128
#define NE   2097152
#define EGRID 1024
#define NPART 1024

// ---------------------------------------------------------------------------
// init: Qua1[u][d] = x_ue[u]*Wm1_ua[0][d] + bm1_ua[d];  Pau1[a][d] = bm1_au[d]
// ---------------------------------------------------------------------------
__global__ __launch_bounds__(256) void init_kernel(
    const float* __restrict__ x_ue, const float* __restrict__ Wm1_ua,
    const float* __restrict__ bm1_ua, const float* __restrict__ bm1_au,
    float* __restrict__ Qua, float* __restrict__ Pau)
{
    int i = blockIdx.x * 256 + threadIdx.x;   // grid covers N_UE*32 exactly
    int u = i >> 5, d = i & 31;
    Qua[i] = fmaf(x_ue[u], Wm1_ua[d], bm1_ua[d]);
    if (i < N_AP * 32) Pau[i] = bm1_au[d];
}

// ---------------------------------------------------------------------------
// Fused edge kernel.
// EUPD: e_new = relu(Rue[src] + Rap[dst] + e @ Ec(2x2))   (Rap has bias folded)
// MSG : m_ua = relu(Qua[src] + e_ua·u01) -> LDS agg_ap ; flush to partials
//       m_au = relu(Pau[dst] + e_au·w01) -> global atomic agg_ue (coalesced line)
// 32-lane groups; chunk of 32 edges staged via LDS for broadcast.
// ---------------------------------------------------------------------------
template<bool EUPD, bool MSG>
__global__ __launch_bounds__(256) void edge_kernel(
    const int* __restrict__ src, const int* __restrict__ dst,
    const float2* __restrict__ eua_in, const float2* __restrict__ eau_in,
    float2* __restrict__ eua_out, float2* __restrict__ eau_out,
    const float2* __restrict__ RueA, const float2* __restrict__ RapA, const float* __restrict__ EcA,
    const float2* __restrict__ RueB, const float2* __restrict__ RapB, const float* __restrict__ EcB,
    const float* __restrict__ Qua, const float* __restrict__ Pau,
    const float* __restrict__ cu, const float* __restrict__ cw,
    float* __restrict__ agg_ue, float* __restrict__ partial_ap)
{
    __shared__ float aggap_s[N_AP * 32];
    __shared__ float pau_s[N_AP * 32];
    __shared__ int2   stg_sd[8][32];
    __shared__ float4 stg_ef[8][32];

    const int tid  = threadIdx.x;
    const int lane = tid & 31;
    const int g    = tid >> 5;

    float u0 = 0.f, u1 = 0.f, w0 = 0.f, w1 = 0.f;
    if (MSG) {
        u0 = cu[lane]; u1 = cu[32 + lane];
        w0 = cw[lane]; w1 = cw[32 + lane];
        for (int i = tid; i < N_AP * 32; i += 256) { aggap_s[i] = 0.f; pau_s[i] = Pau[i]; }
    }
    float c00=0.f,c01=0.f,c10=0.f,c11=0.f, d00=0.f,d01=0.f,d10=0.f,d11=0.f;
    if (EUPD) {
        c00 = EcA[0]; c01 = EcA[1]; c10 = EcA[2]; c11 = EcA[3];
        d00 = EcB[0]; d01 = EcB[1]; d10 = EcB[2]; d11 = EcB[3];
    }
    if (MSG) __syncthreads();

    const int group   = (blockIdx.x * 256 + tid) >> 5;
    const int ngroups = (gridDim.x * 256) >> 5;

    for (int base = group * 32; base < NE; base += ngroups * 32) {
        const int e = base + lane;
        int s  = src[e];
        int dt = dst[e];
        float2 ea = eua_in[e];
        float2 eb = eau_in[e];
        if (EUPD) {
            float2 ru = RueA[s], ra = RapA[dt];
            float n0 = fmaxf(ru.x + ra.x + ea.x * c00 + ea.y * c10, 0.f);
            float n1 = fmaxf(ru.y + ra.y + ea.x * c01 + ea.y * c11, 0.f);
            float2 rv = RueB[s], rb = RapB[dt];
            float m0 = fmaxf(rv.x + rb.x + eb.x * d00 + eb.y * d10, 0.f);
            float m1 = fmaxf(rv.y + rb.y + eb.x * d01 + eb.y * d11, 0.f);
            ea = make_float2(n0, n1);
            eb = make_float2(m0, m1);
            eua_out[e] = ea;
            eau_out[e] = eb;
        }
        if (MSG) {
            stg_sd[g][lane] = make_int2(s, dt);
            stg_ef[g][lane] = make_float4(ea.x, ea.y, eb.x, eb.y);
            #pragma unroll
            for (int j = 0; j < 32; ++j) {
                int2   sd = stg_sd[g][j];          // broadcast ds_read
                float4 ef = stg_ef[g][j];          // broadcast ds_read
                float q   = Qua[sd.x * 32 + lane]; // coalesced 128B gather (L2)
                float mua = fmaxf(fmaf(ef.x, u0, fmaf(ef.y, u1, q)), 0.f);
                atomicAdd(&aggap_s[sd.y * 32 + lane], mua);       // LDS atomic
                float p   = pau_s[sd.y * 32 + lane];
                float mau = fmaxf(fmaf(ef.z, w0, fmaf(ef.w, w1, p)), 0.f);
                atomicAdd(&agg_ue[sd.x * 32 + lane], mau);        // 1 line/edge
            }
        }
    }
    if (MSG) {
        __syncthreads();
        float* outp = partial_ap + (size_t)blockIdx.x * (N_AP * 32);
        for (int i = tid; i < N_AP * 32; i += 256) outp[i] = aggap_s[i];
    }
}

// ---------------------------------------------------------------------------
// UE node update + next-layer tables (+ power head for LAST)
// ---------------------------------------------------------------------------
template<bool FIRST, bool LAST>
__global__ __launch_bounds__(256) void node_ue_kernel(
    const float* __restrict__ x_prev, const float* __restrict__ agg_ue,
    const float* __restrict__ Wu, const float* __restrict__ bu,
    const float* __restrict__ Wm_next, const float* __restrict__ bm_next,
    const float* __restrict__ WeUa, const float* __restrict__ WeUb,
    const float* __restrict__ Wp1, const float* __restrict__ bp1,
    const float* __restrict__ Wp2, const float* __restrict__ bp2,
    float* __restrict__ x_new, float* __restrict__ Qua_next,
    float2* __restrict__ RueA, float2* __restrict__ RueB,
    float2* __restrict__ ue_out)
{
    constexpr int KIN = FIRST ? 33 : 64;
    __shared__ float Wu_s[64 * 32];
    __shared__ float Wm_s[32 * 32];
    __shared__ float WeA_s[64], WeB_s[64];
    __shared__ float bu_s[32], bm_s[32];
    __shared__ float Wp1_s[32 * 16], bp1_s[16], Wp2_s[16];

    const int tid = threadIdx.x;
    for (int i = tid; i < KIN * 32; i += 256) Wu_s[i] = Wu[i];
    if (tid < 32) bu_s[tid] = bu[tid];
    if (!LAST) {
        for (int i = tid; i < 1024; i += 256) Wm_s[i] = Wm_next[i];
        if (tid < 32) bm_s[tid] = bm_next[tid];
    }
    if (tid < 64) { WeA_s[tid] = WeUa[tid]; WeB_s[tid] = WeUb[tid]; }
    if (LAST) {
        for (int i = tid; i < 512; i += 256) Wp1_s[i] = Wp1[i];
        if (tid < 16) { bp1_s[tid] = bp1[tid]; Wp2_s[tid] = Wp2[tid]; }
    }
    __syncthreads();

    const int u = blockIdx.x * 256 + tid;
    float in[KIN];
    if (FIRST) {
        in[0] = x_prev[u];
        #pragma unroll
        for (int k = 0; k < 32; ++k) in[1 + k] = agg_ue[u * 32 + k];
    } else {
        #pragma unroll
        for (int k = 0; k < 32; ++k) in[k] = x_prev[u * 32 + k];
        #pragma unroll
        for (int k = 0; k < 32; ++k) in[32 + k] = agg_ue[u * 32 + k];
    }
    float out[32];
    #pragma unroll
    for (int d = 0; d < 32; ++d) {
        float acc = bu_s[d];
        #pragma unroll
        for (int k = 0; k < KIN; ++k) acc = fmaf(in[k], Wu_s[k * 32 + d], acc);
        out[d] = fmaxf(acc, 0.f);
    }
    #pragma unroll
    for (int d = 0; d < 32; ++d) x_new[u * 32 + d] = out[d];
    if (!LAST) {
        #pragma unroll
        for (int d = 0; d < 32; ++d) {
            float acc = bm_s[d];
            #pragma unroll
            for (int k = 0; k < 32; ++k) acc = fmaf(out[k], Wm_s[k * 32 + d], acc);
            Qua_next[u * 32 + d] = acc;
        }
    }
    float r0 = 0.f, r1 = 0.f, s0 = 0.f, s1 = 0.f;
    #pragma unroll
    for (int k = 0; k < 32; ++k) {
        r0 = fmaf(out[k], WeA_s[k * 2],     r0);
        r1 = fmaf(out[k], WeA_s[k * 2 + 1], r1);
        s0 = fmaf(out[k], WeB_s[k * 2],     s0);
        s1 = fmaf(out[k], WeB_s[k * 2 + 1], s1);
    }
    RueA[u] = make_float2(r0, r1);
    RueB[u] = make_float2(s0, s1);
    if (LAST) {
        float z = bp2[0];
        #pragma unroll
        for (int j = 0; j < 16; ++j) {
            float h = bp1_s[j];
            #pragma unroll
            for (int k = 0; k < 32; ++k) h = fmaf(out[k], Wp1_s[k * 16 + j], h);
            z = fmaf(fmaxf(h, 0.f), Wp2_s[j], z);
        }
        float pw = 1.f / (1.f + expf(-z));
        ue_out[u] = make_float2(out[0], pw);
    }
}

// ---------------------------------------------------------------------------
// AP: reduce partials -> agg_ap, node update, next-layer tables
// ---------------------------------------------------------------------------
template<bool FIRST, bool LAST>
__global__ __launch_bounds__(256) void node_ap_kernel(
    const float* __restrict__ partial,
    const float* __restrict__ x_prev,
    const float* __restrict__ Wu, const float* __restrict__ bu,
    const float* __restrict__ Wm_next, const float* __restrict__ bm_next,
    const float* __restrict__ WeA, const float* __restrict__ beA,
    const float* __restrict__ WeB, const float* __restrict__ beB,
    float* __restrict__ x_new, float* __restrict__ Pau_next,
    float2* __restrict__ RapA, float2* __restrict__ RapB)
{
    __shared__ float red[256];
    __shared__ float agg_s[32];
    __shared__ float xnew_s[32];
    const int a = blockIdx.x, tid = threadIdx.x;
    const int d = tid & 31, p0 = tid >> 5;
    float acc = 0.f;
    for (int p = p0; p < NPART; p += 8)
        acc += partial[(size_t)p * (N_AP * 32) + a * 32 + d];
    red[tid] = acc;
    __syncthreads();
    if (tid < 32) {
        float s = 0.f;
        #pragma unroll
        for (int i = 0; i < 8; ++i) s += red[i * 32 + tid];
        agg_s[tid] = s;
    }
    __syncthreads();
    if (tid < 32) {
        float acc2 = bu[d];
        if (FIRST) {
            #pragma unroll
            for (int k = 0; k < 32; ++k) acc2 = fmaf(agg_s[k], Wu[k * 32 + d], acc2);
        } else {
            #pragma unroll
            for (int k = 0; k < 32; ++k) acc2 = fmaf(x_prev[a * 32 + k], Wu[k * 32 + d], acc2);
            #pragma unroll
            for (int k = 0; k < 32; ++k) acc2 = fmaf(agg_s[k], Wu[(32 + k) * 32 + d], acc2);
        }
        float xn = fmaxf(acc2, 0.f);
        xnew_s[d] = xn;
        x_new[a * 32 + d] = xn;
    }
    __syncthreads();
    if (!LAST) {
        if (tid < 32) {
            float acc3 = bm_next[d];
            #pragma unroll
            for (int k = 0; k < 32; ++k) acc3 = fmaf(xnew_s[k], Wm_next[k * 32 + d], acc3);
            Pau_next[a * 32 + d] = acc3;
        }
    }
    if (tid == 0) {
        float q0 = beA[0], q1 = beA[1], t0 = beB[0], t1 = beB[1];
        #pragma unroll
        for (int k = 0; k < 32; ++k) {
            q0 = fmaf(xnew_s[k], WeA[k * 2],     q0);
            q1 = fmaf(xnew_s[k], WeA[k * 2 + 1], q1);
            t0 = fmaf(xnew_s[k], WeB[k * 2],     t0);
            t1 = fmaf(xnew_s[k], WeB[k * 2 + 1], t1);
        }
        RapA[a] = make_float2(q0, q1);
        RapB[a] = make_float2(t0, t1);
    }
}

// ---------------------------------------------------------------------------
extern "C" void kernel_launch(void* const* d_in, const int* in_sizes, int n_in,
                              void* d_out_v, int out_size, void* d_ws, size_t ws_size,
                              hipStream_t stream)
{
    const float*  x_ue   = (const float*)d_in[0];
    const float2* e0ua   = (const float2*)d_in[1];
    const float2* e0au   = (const float2*)d_in[2];
    const int*    src    = (const int*)d_in[3];
    const int*    dst    = (const int*)d_in[4];
    const float* Wm1_ua = (const float*)d_in[5];
    const float* bm1_ua = (const float*)d_in[6];
    const float* Wm1_au = (const float*)d_in[7];
    const float* bm1_au = (const float*)d_in[8];
    const float* Wu1_ap = (const float*)d_in[9];
    const float* bu1_ap = (const float*)d_in[10];
    const float* Wu1_ue = (const float*)d_in[11];
    const float* bu1_ue = (const float*)d_in[12];
    const float* We1_ua = (const float*)d_in[13];
    const float* be1_ua = (const float*)d_in[14];
    const float* We1_au = (const float*)d_in[15];
    const float* be1_au = (const float*)d_in[16];
    const float* Wm_ua  = (const float*)d_in[17];
    const float* bm_ua  = (const float*)d_in[18];
    const float* Wm_au  = (const float*)d_in[19];
    const float* bm_au  = (const float*)d_in[20];
    const float* Wu_ap  = (const float*)d_in[21];
    const float* bu_ap  = (const float*)d_in[22];
    const float* Wu_ue  = (const float*)d_in[23];
    const float* bu_ue  = (const float*)d_in[24];
    const float* We_ua  = (const float*)d_in[25];
    const float* be_ua  = (const float*)d_in[26];
    const float* We_au  = (const float*)d_in[27];
    const float* be_au  = (const float*)d_in[28];
    const float* Wp1    = (const float*)d_in[29];
    const float* bp1    = (const float*)d_in[30];
    const float* Wp2    = (const float*)d_in[31];
    const float* bp2    = (const float*)d_in[32];

    float*  outp    = (float*)d_out_v;
    float2* out_ue  = (float2*)outp;                              // [16384][2]
    float*  out_ap  = outp + N_UE * 2;                            // [128][32]
    float2* out_eua = (float2*)(outp + N_UE * 2 + N_AP * 32);     // [E][2]
    float2* out_eau = (float2*)(outp + N_UE * 2 + N_AP * 32 + (size_t)NE * 2);

    float* ws = (float*)d_ws;
    float* x_ueA  = ws;          ws += N_UE * 32;
    float* x_ueB  = ws;          ws += N_UE * 32;
    float* x_apA  = ws;          ws += N_AP * 32;
    float* x_apB  = ws;          ws += N_AP * 32;
    float* agg_ue = ws;          ws += N_UE * 32;
    float* Qua    = ws;          ws += N_UE * 32;
    float* Pau    = ws;          ws += N_AP * 32;
    float2* RueA  = (float2*)ws; ws += N_UE * 2;
    float2* RueB  = (float2*)ws; ws += N_UE * 2;
    float2* RapA  = (float2*)ws; ws += N_AP * 2;
    float2* RapB  = (float2*)ws; ws += N_AP * 2;
    float2* eAua  = (float2*)ws; ws += (size_t)NE * 2;
    float2* eAau  = (float2*)ws; ws += (size_t)NE * 2;
    float* partial = ws;         ws += (size_t)NPART * N_AP * 32;

    dim3 blk(256);
    const size_t aggBytes = (size_t)N_UE * 32 * sizeof(float);

    init_kernel<<<N_UE * 32 / 256, blk, 0, stream>>>(x_ue, Wm1_ua, bm1_ua, bm1_au, Qua, Pau);

    // ---- layer 1: messages + aggregation ----
    hipMemsetAsync(agg_ue, 0, aggBytes, stream);
    edge_kernel<false, true><<<EGRID, blk, 0, stream>>>(
        src, dst, e0ua, e0au, nullptr, nullptr,
        nullptr, nullptr, nullptr, nullptr, nullptr, nullptr,
        Qua, Pau, Wm1_ua + 32, Wm1_au, agg_ue, partial);
    node_ue_kernel<true, false><<<N_UE / 256, blk, 0, stream>>>(
        x_ue, agg_ue, Wu1_ue, bu1_ue, Wm_ua, bm_ua, We1_ua, We1_au,
        nullptr, nullptr, nullptr, nullptr,
        x_ueA, Qua, RueA, RueB, nullptr);
    node_ap_kernel<true, false><<<N_AP, blk, 0, stream>>>(
        partial, nullptr, Wu1_ap, bu1_ap, Wm_au, bm_au,
        We1_ua + 64, be1_ua, We1_au + 64, be1_au,
        x_apA, Pau, RapA, RapB);

    // ---- edge-update 1 fused with layer-2 messages ----
    hipMemsetAsync(agg_ue, 0, aggBytes, stream);
    edge_kernel<true, true><<<EGRID, blk, 0, stream>>>(
        src, dst, e0ua, e0au, eAua, eAau,
        RueA, RapA, We1_ua + 128, RueB, RapB, We1_au + 128,
        Qua, Pau, Wm_ua + 1024, Wm_au + 1024, agg_ue, partial);
    node_ue_kernel<false, false><<<N_UE / 256, blk, 0, stream>>>(
        x_ueA, agg_ue, Wu_ue, bu_ue, Wm_ua + 1088, bm_ua + 32, We_ua, We_au,
        nullptr, nullptr, nullptr, nullptr,
        x_ueB, Qua, RueA, RueB, nullptr);
    node_ap_kernel<false, false><<<N_AP, blk, 0, stream>>>(
        partial, x_apA, Wu_ap, bu_ap, Wm_au + 1088, bm_au + 32,
        We_ua + 64, be_ua, We_au + 64, be_au,
        x_apB, Pau, RapA, RapB);

    // ---- edge-update 2 fused with layer-3 messages ----
    hipMemsetAsync(agg_ue, 0, aggBytes, stream);
    edge_kernel<true, true><<<EGRID, blk, 0, stream>>>(
        src, dst, eAua, eAau, out_eua, out_eau,
        RueA, RapA, We_ua + 128, RueB, RapB, We_au + 128,
        Qua, Pau, Wm_ua + 2112, Wm_au + 2112, agg_ue, partial);
    node_ue_kernel<false, false><<<N_UE / 256, blk, 0, stream>>>(
        x_ueB, agg_ue, Wu_ue + 2048, bu_ue + 32, Wm_ua + 2176, bm_ua + 64,
        We_ua + 132, We_au + 132,
        nullptr, nullptr, nullptr, nullptr,
        x_ueA, Qua, RueA, RueB, nullptr);
    node_ap_kernel<false, false><<<N_AP, blk, 0, stream>>>(
        partial, x_apB, Wu_ap + 2048, bu_ap + 32, Wm_au + 2176, bm_au + 64,
        We_ua + 196, be_ua + 2, We_au + 196, be_au + 2,
        x_apA, Pau, RapA, RapB);

    // ---- edge-update 3 fused with layer-4 messages ----
    hipMemsetAsync(agg_ue, 0, aggBytes, stream);
    edge_kernel<true, true><<<EGRID, blk, 0, stream>>>(
        src, dst, out_eua, out_eau, eAua, eAau,
        RueA, RapA, We_ua + 260, RueB, RapB, We_au + 260,
        Qua, Pau, Wm_ua + 3200, Wm_au + 3200, agg_ue, partial);
    node_ue_kernel<false, true><<<N_UE / 256, blk, 0, stream>>>(
        x_ueA, agg_ue, Wu_ue + 4096, bu_ue + 64, nullptr, nullptr,
        We_ua + 264, We_au + 264,
        Wp1, bp1, Wp2, bp2,
        x_ueB, nullptr, RueA, RueB, out_ue);
    node_ap_kernel<false, true><<<N_AP, blk, 0, stream>>>(
        partial, x_apA, Wu_ap + 4096, bu_ap + 64, nullptr, nullptr,
        We_ua + 328, be_ua + 4, We_au + 328, be_au + 4,
        out_ap, nullptr, RapA, RapB);

    // ---- final edge update (layer 4) ----
    edge_kernel<true, false><<<EGRID, blk, 0, stream>>>(
        src, dst, eAua, eAau, out_eua, out_eau,
        RueA, RapA, We_ua + 392, RueB, RapB, We_au + 392,
        nullptr, nullptr, nullptr, nullptr, nullptr, nullptr);
}